// Round 19
// baseline (29335.718 us; speedup 1.0000x reference)
//
#include <hip/hip_runtime.h>

#define NBLK 256
#define NTHR 512

typedef float f32x4 __attribute__((ext_vector_type(4)));
typedef unsigned int u32;

// ---------------- math helpers ----------------
__device__ __forceinline__ float sigm(float x){ return 1.f/(1.f+__expf(-x)); }
__device__ __forceinline__ float tanh_(float x){ return 1.f - 2.f/(__expf(2.f*x)+1.f); }

__device__ __forceinline__ float wred_sum(float v){
  #pragma unroll
  for (int off=32; off; off>>=1) v += __shfl_xor(v, off, 64);
  return v;
}

// bf16 pack/unpack
__device__ __forceinline__ u32 cvtpk(float lo, float hi){
  u32 r; asm("v_cvt_pk_bf16_f32 %0,%1,%2":"=v"(r):"v"(lo),"v"(hi)); return r;
}
__device__ __forceinline__ float bflo(u32 u){ return __uint_as_float(u<<16); }
__device__ __forceinline__ float bfhi(u32 u){ return __uint_as_float(u & 0xFFFF0000u); }

// agent-coherent (sc1) store/load
__device__ __forceinline__ void st_sysu(u32* p, u32 v){
  __hip_atomic_store(p, v, __ATOMIC_RELAXED, __HIP_MEMORY_SCOPE_AGENT);
}
__device__ __forceinline__ u32 aldu(const u32* p){
  return __hip_atomic_load(p, __ATOMIC_RELAXED, __HIP_MEMORY_SCOPE_AGENT);
}

__device__ __forceinline__ void vmwait0(){
  asm volatile("s_waitcnt vmcnt(0)" ::: "memory");
  __builtin_amdgcn_sched_barrier(0);
}
__device__ __forceinline__ void lgkm0(){
  asm volatile("s_waitcnt lgkmcnt(0)" ::: "memory");
  __builtin_amdgcn_sched_barrier(0);
}

// DIRECT-POLL flag barrier (128 WGs/domain), epoch-based, contention-free.
// Each WG stores its OWN flag (no atomic serialization); every WG's wave 0
// polls ALL 128 flags in parallel (2 coalesced loads/lane + __all ballot).
// Critical path = slowest flag store -> own detect (~2 fabric RTs, no
// root/release hop). Built on __syncthreads (full compiler drains, proven).
// barD layout (u32): [256..383] = flags.
__device__ __forceinline__ void gsync(unsigned* barD, int idx, unsigned& ep){
  ++ep;
  __builtin_amdgcn_s_waitcnt(0);          // all prior sc1 stores at coherence pt
  __syncthreads();                         // all waves drained
  const int tid = threadIdx.x;
  if (tid < 64){
    if (tid == 0) st_sysu(barD + 256 + idx, ep);
    for (;;){
      const u32 f0 = aldu(barD + 256 + tid);
      const u32 f1 = aldu(barD + 320 + tid);
      if (__all((f0 >= ep) && (f1 >= ep))) break;
      __builtin_amdgcn_s_sleep(2);
    }
  }
  __syncthreads();
}

// ---------------- LSTM layer: (jt,bt) = 128x2 tiling (r13/r17, proven) ----
template<bool L0T>
__device__ __forceinline__ void lstm_layer(
    int jt, int bt, int tid,
    const float (&wt)[2][8][2], const float (&wx)[2][4],
    float brA, float brB,
    const u32* __restrict__ inu, float* sc_c,
    u32* __restrict__ dstA, int strA,
    u32* __restrict__ dstB, int strB,
    u32* stage, float* scr, u32* xsu, float* sG4,
    const float* __restrict__ tgt, int t)
{
  const int lane = tid & 63, r = tid >> 6;
  const u32* src = inu + bt*16384;

  if (L0T){
    #pragma unroll
    for (int i=0;i<3;++i){
      const int flat = tid + (i<<9);
      if (flat < 1280){
        const int row = flat/40, col = flat - row*40;
        const float* q = tgt + ((((bt<<5)+row)<<8) + t)*80 + (col<<1);
        xsu[flat] = cvtpk(q[0], q[1]);
      }
    }
  }
  uint4 ld[8];
  #pragma unroll
  for (int i=0;i<8;++i){
    const u32* p = src + (i<<11) + (tid<<2);
    asm volatile("global_load_dwordx4 %0, %1, off sc0 sc1" : "=v"(ld[i]) : "v"(p));
  }
  vmwait0();
  #pragma unroll
  for (int i=0;i<8;++i) *(uint4*)(stage + (i<<11) + (tid<<2)) = ld[i];
  __syncthreads();                                   // stage visible

  float* sw = scr + r*1024;
  #pragma unroll 1
  for (int ch=0; ch<4; ++ch){
    float pv0[8], pv1[8];
    #pragma unroll
    for (int bb=0; bb<8; ++bb){
      const u32* rowp = stage + ((ch<<3)+bb)*512 + lane;
      float a0=0.f,a1=0.f,a2=0.f,a3=0.f, c0=0.f,c1=0.f,c2=0.f,c3=0.f;
      #pragma unroll
      for (int i=0;i<8;i+=2){
        const u32 e0 = rowp[(i<<6)];
        const u32 e1 = rowp[((i+1)<<6)];
        const float f0=bflo(e0), f1=bfhi(e0), f2=bflo(e1), f3=bfhi(e1);
        a0 = fmaf(wt[0][i][0],   f0, a0);
        a1 = fmaf(wt[0][i][1],   f1, a1);
        a2 = fmaf(wt[0][i+1][0], f2, a2);
        a3 = fmaf(wt[0][i+1][1], f3, a3);
        c0 = fmaf(wt[1][i][0],   f0, c0);
        c1 = fmaf(wt[1][i][1],   f1, c1);
        c2 = fmaf(wt[1][i+1][0], f2, c2);
        c3 = fmaf(wt[1][i+1][1], f3, c3);
      }
      if (L0T && lane < 20){
        const int lrow = (ch<<3)+bb;
        const u32 x0 = xsu[lrow*40 + (lane<<1)];
        const u32 x1 = xsu[lrow*40 + (lane<<1) + 1];
        const float g0=bflo(x0), g1=bfhi(x0), g2=bflo(x1), g3=bfhi(x1);
        a0 = fmaf(wx[0][0], g0, a0); a1 = fmaf(wx[0][1], g1, a1);
        a2 = fmaf(wx[0][2], g2, a2); a3 = fmaf(wx[0][3], g3, a3);
        c0 = fmaf(wx[1][0], g0, c0); c1 = fmaf(wx[1][1], g1, c1);
        c2 = fmaf(wx[1][2], g2, c2); c3 = fmaf(wx[1][3], g3, c3);
      }
      pv0[bb] = (a0+a1)+(a2+a3);
      pv1[bb] = (c0+c1)+(c2+c3);
    }
    #pragma unroll
    for (int bb=0; bb<8; ++bb){
      sw[(bb<<6) + lane]       = pv0[bb];
      sw[512 + (bb<<6) + lane] = pv1[bb];
    }
    lgkm0();
    {
      const int bb2 = lane>>3, m = lane&7;
      const float* pp = sw + (bb2<<6) + (m<<3);
      float v0 = ((pp[0]+pp[1])+(pp[2]+pp[3])) + ((pp[4]+pp[5])+(pp[6]+pp[7]));
      const float* pq = pp + 512;
      float v1 = ((pq[0]+pq[1])+(pq[2]+pq[3])) + ((pq[4]+pq[5])+(pq[6]+pq[7]));
      v0 += __shfl_xor(v0,1,64); v0 += __shfl_xor(v0,2,64); v0 += __shfl_xor(v0,4,64);
      v1 += __shfl_xor(v1,1,64); v1 += __shfl_xor(v1,2,64); v1 += __shfl_xor(v1,4,64);
      if (m==0){
        sG4[(((ch<<3)+bb2)<<4) + r]     = v0 + brA;
        sG4[(((ch<<3)+bb2)<<4) + r + 8] = v1 + brB;
      }
    }
  }
  lgkm0();
  __syncthreads();                                   // sG4 visible

  if (tid < 128){
    const int b = tid>>2, jl = tid&3;
    const float* g = sG4 + (b<<4) + (jl<<2);
    const float gi = sigm(g[0]), gf = sigm(g[1]);
    const float gg = tanh_(g[2]), go = sigm(g[3]);
    const float cn = gf*sc_c[tid] + gi*gg;
    sc_c[tid] = cn;
    const float hn = go*tanh_(cn);
    const float hn1 = __shfl(hn, tid^1, 64);
    if (!(tid&1)){
      const u32 hp = cvtpk(hn, hn1);
      const int gb = (bt<<5) + b;
      const int col = (jt<<1) + (jl>>1);
      st_sysu(dstA + gb*strA + col, hp);
      st_sysu(dstB + gb*strB + col, hp);
    }
  }
}

// ---- ws layout (after 8KB barrier area), in UINTS ----
#define ENC_OFF  475648
#define ENC_CNT  8388608
#define WQ_OFF   8864256
#define WQ_CNT   131072

__global__ __launch_bounds__(NTHR, 2)
void sd_kernel(const float* __restrict__ tgt,  const float* __restrict__ enc,
               const int*   __restrict__ lens,
               const float* __restrict__ Wih0, const float* __restrict__ Whh0, const float* __restrict__ b0v,
               const float* __restrict__ Wih1, const float* __restrict__ Whh1, const float* __restrict__ b1v,
               const float* __restrict__ Wih2, const float* __restrict__ Whh2, const float* __restrict__ b2v,
               const float* __restrict__ Wq,   const float* __restrict__ Wfc,  const float* __restrict__ bfc,
               float* __restrict__ out, void* __restrict__ wsv, int ebf)
{
  unsigned* bar = (unsigned*)wsv;
  u32* wsu = (u32*)((char*)wsv + 8192);
  u32* IN0u = wsu;
  u32* IN1u = wsu + 65536;
  u32* IN2u = wsu + 131072;
  u32* H2u  = wsu + 196608;
  u32* encbfu = wsu + ENC_OFF;
  u32* wqbfu  = wsu + WQ_OFF;

  const int w = blockIdx.x, tid = threadIdx.x;
  const int lane = tid & 63, r = tid >> 6;
  const int d = w & 1;                 // sync domain / batch half
  const int idx = w >> 1;              // 0..127 within domain
  const int jt = idx, bt = d;
  unsigned* barD = bar + d*1024;
  unsigned ep = 0;

  __shared__ __attribute__((aligned(16))) u32 SM[26752];
  u32*   stage = SM;
  float* scr   = (float*)(SM + 16384);
  u32*   xsu   = SM + 24576;
  float* sG4   = (float*)(SM + 25856);
  float* sc_c  = (float*)(SM + 26368);
  // attn aliases into stage region (disjoint phases):
  float* sBig   = (float*)SM;              // 4096 f
  float* sVec   = (float*)(SM + 4096);     // 512 f
  float* sSmall = (float*)(SM + 4608);     // 16 f

  // ---- prologue: weights -> registers (2 rows per wave) ----
  const int wrowA = ((r&3)<<9) + (jt<<2) + (r>>2);
  const int wrowB = wrowA + 2;
  float w0r[2][8][2], w1r[2][8][2], w2r[2][8][2], wx0[2][4];
  #pragma unroll
  for (int s=0;s<2;++s){
    const int wr = s ? wrowB : wrowA;
    #pragma unroll
    for (int i=0;i<8;++i){
      const int k = 2*(lane + (i<<6));
      if (k < 512){
        w0r[s][i][0] = Wih0[wr*592 + 80 + k];   w0r[s][i][1] = Wih0[wr*592 + 81 + k];
        w1r[s][i][0] = Wih1[(wr<<9) + k];       w1r[s][i][1] = Wih1[(wr<<9) + k + 1];
        w2r[s][i][0] = Wih2[(wr<<9) + k];       w2r[s][i][1] = Wih2[(wr<<9) + k + 1];
      } else {
        w0r[s][i][0] = Whh0[(wr<<9) + k - 512]; w0r[s][i][1] = Whh0[(wr<<9) + k - 511];
        w1r[s][i][0] = Whh1[(wr<<9) + k - 512]; w1r[s][i][1] = Whh1[(wr<<9) + k - 511];
        w2r[s][i][0] = Whh2[(wr<<9) + k - 512]; w2r[s][i][1] = Whh2[(wr<<9) + k - 511];
      }
    }
    #pragma unroll
    for (int m=0;m<4;++m)
      wx0[s][m] = (lane < 20) ? Wih0[wr*592 + (lane<<2) + m] : 0.f;
  }
  const float br0A=b0v[wrowA], br0B=b0v[wrowB];
  const float br1A=b1v[wrowA], br1B=b1v[wrowB];
  const float br2A=b2v[wrowA], br2B=b2v[wrowB];

  if (tid < 384) sc_c[tid] = 0.f;

  // ---- domain-local init: zero state (106496 u32/domain) ----
  for (int i = idx*NTHR + tid; i < 106496; i += 128*NTHR){
    u32* p;
    if (i < 98304){
      const int buf = i >> 15;
      const int r2  = i & 32767;
      const int par = r2 >> 14;
      const int r3  = r2 & 16383;
      const int b   = (d<<5) + (r3 >> 9);
      const int c   = r3 & 511;
      u32* base = (buf==0) ? IN0u : (buf==1) ? IN1u : IN2u;
      p = base + par*32768 + b*512 + c;
    } else {
      const int r3 = i - 98304;
      const int b  = (d<<5) + (r3 >> 8);
      p = H2u + b*256 + (r3 & 255);
    }
    st_sysu(p, 0u);
  }
  if (ebf){
    for (int i = idx*NTHR + tid; i < 4194304; i += 128*NTHR){
      const int gi = (d<<22) + i;
      st_sysu(encbfu + gi, cvtpk(enc[2*(size_t)gi], enc[2*(size_t)gi+1]));
    }
    u32* wqd = wqbfu + d*131072;
    for (int i = idx*NTHR + tid; i < 131072; i += 128*NTHR){
      const int k = i >> 8, ee = (i & 255) << 1;
      st_sysu(wqd + i, cvtpk(Wq[(k<<9) + ee], Wq[(k<<9) + ee + 1]));
    }
  }
  gsync(barD, idx, ep);

  for (int t=0; t<255; ++t){
    const int p = t & 1, np = p ^ 1;
    u32* IN0p = IN0u + p*32768;  u32* IN0n = IN0u + np*32768;
    u32* IN1p = IN1u + p*32768;  u32* IN1n = IN1u + np*32768;
    u32* IN2p = IN2u + p*32768;  u32* IN2n = IN2u + np*32768;

    lstm_layer<true >(jt,bt,tid, w0r, wx0, br0A, br0B, IN0p, sc_c,
                      IN0n+256, 512, IN1p, 512, stage,scr,xsu,sG4, tgt, t);
    gsync(barD,idx,ep);
    lstm_layer<false>(jt,bt,tid, w1r, wx0, br1A, br1B, IN1p, sc_c+128,
                      IN1n+256, 512, IN2p, 512, stage,scr,xsu,sG4, tgt, t);
    gsync(barD,idx,ep);
    lstm_layer<false>(jt,bt,tid, w2r, wx0, br2A, br2B, IN2p, sc_c+256,
                      IN2n+256, 512, H2u, 256, stage,scr,xsu,sG4, tgt, t);
    gsync(barD,idx,ep);

    // ---- attnA': all 128 WGs. (b_loc = idx&31, sq = idx>>5).
    //      q computed redundantly (4x) then 128-row online softmax. ----
    {
      const int b_loc = idx & 31, sq = idx >> 5;
      const int b = (d<<5) + b_loc;
      const int len = lens[b];
      if (tid < 256){
        const u32 u = aldu(H2u + b*256 + tid);
        sVec[2*tid]   = bflo(u);
        sVec[2*tid+1] = bfhi(u);
      }
      __syncthreads();
      // q[e=tid] = sum_k h2[k] * Wq[k][e]
      float qa = 0.f;
      if (ebf){
        const u32* wqb = wqbfu + d*131072 + (tid>>1);
        const u32 sel = tid & 1;
        #pragma unroll 4
        for (int k=0;k<512;++k){
          const u32 u = wqb[k<<8];                   // normal cached (L2-hot)
          qa = fmaf(sVec[k], sel ? bfhi(u) : bflo(u), qa);
        }
      } else {
        const float* wqp = Wq + tid;
        #pragma unroll 4
        for (int k=0;k<512;++k) qa = fmaf(sVec[k], wqp[(size_t)k<<9], qa);
      }
      __syncthreads();                               // h2 reads done
      sVec[tid] = qa;                                // sVec now holds q
      __syncthreads();

      const int wv = tid >> 6;
      const float4 qA = *(const float4*)(sVec + (lane<<3));
      const float4 qB = *(const float4*)(sVec + (lane<<3) + 4);
      float mr = -3.0e38f, lr = 0.f;
      float c0=0,c1=0,c2=0,c3=0,c4=0,c5=0,c6=0,c7=0;
      const float scale = 0.04419417382415922f;      // 1/sqrt(512)
      if (ebf){
        const u32* ebase = encbfu + (((size_t)b)<<17) + (lane<<2);
        #pragma unroll 1
        for (int rr=0; rr<16; ++rr){
          const int srow = (sq<<7) + (wv<<4) + rr;   // wave-uniform
          if (srow >= len) break;                    // rows monotonic
          const uint4 eu = *(const uint4*)(ebase + ((size_t)srow<<8));
          const float e0=bflo(eu.x), e1=bfhi(eu.x), e2=bflo(eu.y), e3=bfhi(eu.y);
          const float e4=bflo(eu.z), e5=bfhi(eu.z), e6=bflo(eu.w), e7=bfhi(eu.w);
          float d0 = qA.x*e0, d1 = qA.y*e1, d2 = qA.z*e2, d3 = qA.w*e3;
          d0 = fmaf(qB.x, e4, d0); d1 = fmaf(qB.y, e5, d1);
          d2 = fmaf(qB.z, e6, d2); d3 = fmaf(qB.w, e7, d3);
          float dd = wred_sum((d0+d1)+(d2+d3));
          const float sc = dd*scale;
          const float mn = fmaxf(mr, sc);
          const float sf = __expf(mr - mn);
          const float pe = __expf(sc - mn);
          lr = fmaf(lr, sf, pe);
          c0 = fmaf(c0, sf, pe*e0); c1 = fmaf(c1, sf, pe*e1);
          c2 = fmaf(c2, sf, pe*e2); c3 = fmaf(c3, sf, pe*e3);
          c4 = fmaf(c4, sf, pe*e4); c5 = fmaf(c5, sf, pe*e5);
          c6 = fmaf(c6, sf, pe*e6); c7 = fmaf(c7, sf, pe*e7);
          mr = mn;
        }
      } else {
        #pragma unroll 1
        for (int rr=0; rr<16; ++rr){
          const int srow = (sq<<7) + (wv<<4) + rr;
          if (srow >= len) break;
          const float* ep2 = enc + (((size_t)(b<<9)+srow)<<9) + (lane<<3);
          const float4 e0v = *(const float4*)(ep2);
          const float4 e1v = *(const float4*)(ep2+4);
          float d0 = qA.x*e0v.x, d1 = qA.y*e0v.y, d2 = qA.z*e0v.z, d3 = qA.w*e0v.w;
          d0 = fmaf(qB.x, e1v.x, d0); d1 = fmaf(qB.y, e1v.y, d1);
          d2 = fmaf(qB.z, e1v.z, d2); d3 = fmaf(qB.w, e1v.w, d3);
          float dd = wred_sum((d0+d1)+(d2+d3));
          const float sc = dd*scale;
          const float mn = fmaxf(mr, sc);
          const float sf = __expf(mr - mn);
          const float pe = __expf(sc - mn);
          lr = fmaf(lr, sf, pe);
          c0 = fmaf(c0, sf, pe*e0v.x); c1 = fmaf(c1, sf, pe*e0v.y);
          c2 = fmaf(c2, sf, pe*e0v.z); c3 = fmaf(c3, sf, pe*e0v.w);
          c4 = fmaf(c4, sf, pe*e1v.x); c5 = fmaf(c5, sf, pe*e1v.y);
          c6 = fmaf(c6, sf, pe*e1v.z); c7 = fmaf(c7, sf, pe*e1v.w);
          mr = mn;
        }
      }
      if (lane==0){ sSmall[wv] = mr; sSmall[8+wv] = lr; }
      {
        float4 v0 = {c0,c1,c2,c3}, v1 = {c4,c5,c6,c7};
        *(float4*)(sBig + (wv<<9) + (lane<<3))     = v0;
        *(float4*)(sBig + (wv<<9) + (lane<<3) + 4) = v1;
      }
      __syncthreads();
      float M = sSmall[0];
      #pragma unroll
      for (int i=1;i<8;++i) M = fmaxf(M, sSmall[i]);
      float L = 0.f, acc = 0.f;
      #pragma unroll
      for (int i=0;i<8;++i){
        const float A = __expf(sSmall[i]-M);
        L   = fmaf(A, sSmall[8+i], L);
        acc = fmaf(A, sBig[(i<<9)+tid], acc);
      }
      float* PC = (float*)(wsu + 212992);            // [4][64][512] f
      st_sysu((u32*)&PC[(((sq<<6)+b)<<9)+tid], __float_as_uint(acc));
      if (tid==0){
        float* MSS = PC + 131072;
        st_sysu((u32*)&MSS[(((sq<<6)+b)<<1)],   __float_as_uint(M));
        st_sysu((u32*)&MSS[(((sq<<6)+b)<<1)+1], __float_as_uint(L));
      }
    }
    gsync(barD,idx,ep);

    // ---- attnB: combine + FC + out (32 WGs/domain: idx<32) ----
    if (idx < 32){
      const int b = (d<<5) + idx;
      float* PC  = (float*)(wsu + 212992);
      float* MSS = PC + 131072;
      const float m0 = __uint_as_float(aldu((u32*)&MSS[(b)<<1]));
      const float S0 = __uint_as_float(aldu((u32*)&MSS[((b)<<1)+1]));
      const float m1 = __uint_as_float(aldu((u32*)&MSS[(64+b)<<1]));
      const float S1 = __uint_as_float(aldu((u32*)&MSS[((64+b)<<1)+1]));
      const float m2 = __uint_as_float(aldu((u32*)&MSS[(128+b)<<1]));
      const float S2 = __uint_as_float(aldu((u32*)&MSS[((128+b)<<1)+1]));
      const float m3 = __uint_as_float(aldu((u32*)&MSS[(192+b)<<1]));
      const float S3 = __uint_as_float(aldu((u32*)&MSS[((192+b)<<1)+1]));
      const float M  = fmaxf(fmaxf(m0,m1), fmaxf(m2,m3));
      const float a0=__expf(m0-M), a1=__expf(m1-M), a2=__expf(m2-M), a3=__expf(m3-M);
      const float inv = 1.f/(a0*S0 + a1*S1 + a2*S2 + a3*S3);
      const float c =
        (a0*__uint_as_float(aldu((u32*)&PC[(b<<9)+tid]))
       + a1*__uint_as_float(aldu((u32*)&PC[((64+b)<<9)+tid]))
       + a2*__uint_as_float(aldu((u32*)&PC[((128+b)<<9)+tid]))
       + a3*__uint_as_float(aldu((u32*)&PC[((192+b)<<9)+tid]))) * inv;
      const float cpr = __shfl(c, tid^1, 64);
      if (!(tid&1)) st_sysu(IN0n + b*512 + (tid>>1), cvtpk(c, cpr));
      sVec[tid] = c;
      __syncthreads();
      if (tid < 80){
        float acc2 = 0.f;
        #pragma unroll 4
        for (int e2=0;e2<512;++e2) acc2 = fmaf(sVec[e2], Wfc[e2*80+tid], acc2);
        out[((size_t)b*255 + t)*80 + tid] = acc2 + bfc[tid];
      }
    }
    gsync(barD,idx,ep);
  }
}

extern "C" void kernel_launch(void* const* d_in, const int* in_sizes, int n_in,
                              void* d_out, int out_size, void* d_ws, size_t ws_size,
                              hipStream_t stream) {
  const float* tgt  = (const float*)d_in[0];
  const float* enc  = (const float*)d_in[1];
  const int*   lens = (const int*)  d_in[2];
  const float* Wih0 = (const float*)d_in[3];
  const float* Whh0 = (const float*)d_in[4];
  const float* b0   = (const float*)d_in[5];
  const float* Wih1 = (const float*)d_in[6];
  const float* Whh1 = (const float*)d_in[7];
  const float* b1   = (const float*)d_in[8];
  const float* Wih2 = (const float*)d_in[9];
  const float* Whh2 = (const float*)d_in[10];
  const float* b2   = (const float*)d_in[11];
  const float* Wq   = (const float*)d_in[12];
  const float* Wfc  = (const float*)d_in[13];
  const float* bfc  = (const float*)d_in[14];

  const size_t need = 8192ull + ((size_t)WQ_OFF + 2ull*(size_t)WQ_CNT)*4ull;
  const int ebf = (ws_size >= need) ? 1 : 0;

  hipMemsetAsync(d_ws, 0, 8192, stream);   // barrier flags (2 domains)
  sd_kernel<<<NBLK, NTHR, 0, stream>>>(tgt, enc, lens,
                                       Wih0, Whh0, b0,
                                       Wih1, Whh1, b1,
                                       Wih2, Whh2, b2,
                                       Wq, Wfc, bfc,
                                       (float*)d_out, d_ws, ebf);
}

// Round 20
// 26806.503 us; speedup vs baseline: 1.0944x; 1.0944x over previous
//
#include <hip/hip_runtime.h>

#define NBLK 256
#define NTHR 512

typedef float f32x4 __attribute__((ext_vector_type(4)));
typedef unsigned int u32;

// ---------------- math helpers ----------------
__device__ __forceinline__ float sigm(float x){ return 1.f/(1.f+__expf(-x)); }
__device__ __forceinline__ float tanh_(float x){ return 1.f - 2.f/(__expf(2.f*x)+1.f); }

__device__ __forceinline__ float wred_sum(float v){
  #pragma unroll
  for (int off=32; off; off>>=1) v += __shfl_xor(v, off, 64);
  return v;
}

// bf16 pack/unpack
__device__ __forceinline__ u32 cvtpk(float lo, float hi){
  u32 r; asm("v_cvt_pk_bf16_f32 %0,%1,%2":"=v"(r):"v"(lo),"v"(hi)); return r;
}
__device__ __forceinline__ float bflo(u32 u){ return __uint_as_float(u<<16); }
__device__ __forceinline__ float bfhi(u32 u){ return __uint_as_float(u & 0xFFFF0000u); }

// agent-coherent (sc1) store/load
__device__ __forceinline__ void st_sysu(u32* p, u32 v){
  __hip_atomic_store(p, v, __ATOMIC_RELAXED, __HIP_MEMORY_SCOPE_AGENT);
}
__device__ __forceinline__ u32 aldu(const u32* p){
  return __hip_atomic_load(p, __ATOMIC_RELAXED, __HIP_MEMORY_SCOPE_AGENT);
}

__device__ __forceinline__ void vmwait0(){
  asm volatile("s_waitcnt vmcnt(0)" ::: "memory");
  __builtin_amdgcn_sched_barrier(0);
}
__device__ __forceinline__ void lgkm0(){
  asm volatile("s_waitcnt lgkmcnt(0)" ::: "memory");
  __builtin_amdgcn_sched_barrier(0);
}

// FLAG-ARRAY domain barrier (128 WGs), epoch-based, contention-free:
// each WG writes its OWN flag (no atomic serialization); root WG's wave 0
// polls all 128 flags in parallel (2 loads/lane + __all ballot); one release
// word polled by members. (r17-proven: best of tree/flag/direct-poll.)
// barD layout (u32): [0]=release, [256..383]=flags.
__device__ __forceinline__ void gsync(unsigned* barD, int idx, unsigned& ep){
  ++ep;
  __builtin_amdgcn_s_waitcnt(0);          // all prior sc1 stores at coherence pt
  __syncthreads();
  const int tid = threadIdx.x;
  if (idx == 0){
    if (tid < 64){
      if (tid == 0) st_sysu(barD + 256, ep);           // own flag
      for (;;){
        const u32 f0 = aldu(barD + 256 + tid);
        const u32 f1 = aldu(barD + 320 + tid);
        if (__all((f0 >= ep) && (f1 >= ep))) break;
        __builtin_amdgcn_s_sleep(1);
      }
      if (tid == 0) st_sysu(barD, ep);                 // release
    }
  } else {
    if (tid == 0){
      st_sysu(barD + 256 + idx, ep);
      while (aldu(barD) < ep) __builtin_amdgcn_s_sleep(1);
    }
  }
  __syncthreads();
}

// ---------------- LSTM layer: (jt,bt) = 128x2 tiling (r13, proven) --------
template<bool L0T>
__device__ __forceinline__ void lstm_layer(
    int jt, int bt, int tid,
    const float (&wt)[2][8][2], const float (&wx)[2][4],
    float brA, float brB,
    const u32* __restrict__ inu, float* sc_c,
    u32* __restrict__ dstA, int strA,
    u32* __restrict__ dstB, int strB,
    u32* stage, float* scr, u32* xsu, float* sG4,
    const float* __restrict__ tgt, int t)
{
  const int lane = tid & 63, r = tid >> 6;
  const u32* src = inu + bt*16384;

  if (L0T){
    #pragma unroll
    for (int i=0;i<3;++i){
      const int flat = tid + (i<<9);
      if (flat < 1280){
        const int row = flat/40, col = flat - row*40;
        const float* q = tgt + ((((bt<<5)+row)<<8) + t)*80 + (col<<1);
        xsu[flat] = cvtpk(q[0], q[1]);
      }
    }
  }
  uint4 ld[8];
  #pragma unroll
  for (int i=0;i<8;++i){
    const u32* p = src + (i<<11) + (tid<<2);
    asm volatile("global_load_dwordx4 %0, %1, off sc0 sc1" : "=v"(ld[i]) : "v"(p));
  }
  vmwait0();
  #pragma unroll
  for (int i=0;i<8;++i) *(uint4*)(stage + (i<<11) + (tid<<2)) = ld[i];
  __syncthreads();                                   // barrier 1: stage visible

  float* sw = scr + r*1024;
  #pragma unroll 1
  for (int ch=0; ch<4; ++ch){
    float pv0[8], pv1[8];
    #pragma unroll
    for (int bb=0; bb<8; ++bb){
      const u32* rowp = stage + ((ch<<3)+bb)*512 + lane;
      float a0=0.f,a1=0.f,a2=0.f,a3=0.f, c0=0.f,c1=0.f,c2=0.f,c3=0.f;
      #pragma unroll
      for (int i=0;i<8;i+=2){
        const u32 e0 = rowp[(i<<6)];
        const u32 e1 = rowp[((i+1)<<6)];
        const float f0=bflo(e0), f1=bfhi(e0), f2=bflo(e1), f3=bfhi(e1);
        a0 = fmaf(wt[0][i][0],   f0, a0);
        a1 = fmaf(wt[0][i][1],   f1, a1);
        a2 = fmaf(wt[0][i+1][0], f2, a2);
        a3 = fmaf(wt[0][i+1][1], f3, a3);
        c0 = fmaf(wt[1][i][0],   f0, c0);
        c1 = fmaf(wt[1][i][1],   f1, c1);
        c2 = fmaf(wt[1][i+1][0], f2, c2);
        c3 = fmaf(wt[1][i+1][1], f3, c3);
      }
      if (L0T && lane < 20){
        const int lrow = (ch<<3)+bb;
        const u32 x0 = xsu[lrow*40 + (lane<<1)];
        const u32 x1 = xsu[lrow*40 + (lane<<1) + 1];
        const float g0=bflo(x0), g1=bfhi(x0), g2=bflo(x1), g3=bfhi(x1);
        a0 = fmaf(wx[0][0], g0, a0); a1 = fmaf(wx[0][1], g1, a1);
        a2 = fmaf(wx[0][2], g2, a2); a3 = fmaf(wx[0][3], g3, a3);
        c0 = fmaf(wx[1][0], g0, c0); c1 = fmaf(wx[1][1], g1, c1);
        c2 = fmaf(wx[1][2], g2, c2); c3 = fmaf(wx[1][3], g3, c3);
      }
      pv0[bb] = (a0+a1)+(a2+a3);
      pv1[bb] = (c0+c1)+(c2+c3);
    }
    #pragma unroll
    for (int bb=0; bb<8; ++bb){
      sw[(bb<<6) + lane]       = pv0[bb];
      sw[512 + (bb<<6) + lane] = pv1[bb];
    }
    lgkm0();
    {
      const int bb2 = lane>>3, m = lane&7;
      const float* pp = sw + (bb2<<6) + (m<<3);
      float v0 = ((pp[0]+pp[1])+(pp[2]+pp[3])) + ((pp[4]+pp[5])+(pp[6]+pp[7]));
      const float* pq = pp + 512;
      float v1 = ((pq[0]+pq[1])+(pq[2]+pq[3])) + ((pq[4]+pq[5])+(pq[6]+pq[7]));
      v0 += __shfl_xor(v0,1,64); v0 += __shfl_xor(v0,2,64); v0 += __shfl_xor(v0,4,64);
      v1 += __shfl_xor(v1,1,64); v1 += __shfl_xor(v1,2,64); v1 += __shfl_xor(v1,4,64);
      if (m==0){
        sG4[(((ch<<3)+bb2)<<4) + r]     = v0 + brA;
        sG4[(((ch<<3)+bb2)<<4) + r + 8] = v1 + brB;
      }
    }
  }
  lgkm0();
  __syncthreads();                                   // barrier 2: sG4 visible

  if (tid < 128){
    const int b = tid>>2, jl = tid&3;
    const float* g = sG4 + (b<<4) + (jl<<2);
    const float gi = sigm(g[0]), gf = sigm(g[1]);
    const float gg = tanh_(g[2]), go = sigm(g[3]);
    const float cn = gf*sc_c[tid] + gi*gg;
    sc_c[tid] = cn;
    const float hn = go*tanh_(cn);
    const float hn1 = __shfl(hn, tid^1, 64);
    if (!(tid&1)){
      const u32 hp = cvtpk(hn, hn1);
      const int gb = (bt<<5) + b;
      const int col = (jt<<1) + (jl>>1);
      st_sysu(dstA + gb*strA + col, hp);
      st_sysu(dstB + gb*strB + col, hp);
    }
  }
}

// ---- ws layout (after 8KB barrier area), in UINTS ----
#define ENC_OFF  475648
#define ENC_CNT  8388608
#define WQ_OFF   8864256
#define WQ_CNT   131072

__global__ __launch_bounds__(NTHR, 2)
void sd_kernel(const float* __restrict__ tgt,  const float* __restrict__ enc,
               const int*   __restrict__ lens,
               const float* __restrict__ Wih0, const float* __restrict__ Whh0, const float* __restrict__ b0v,
               const float* __restrict__ Wih1, const float* __restrict__ Whh1, const float* __restrict__ b1v,
               const float* __restrict__ Wih2, const float* __restrict__ Whh2, const float* __restrict__ b2v,
               const float* __restrict__ Wq,   const float* __restrict__ Wfc,  const float* __restrict__ bfc,
               float* __restrict__ out, void* __restrict__ wsv, int ebf)
{
  unsigned* bar = (unsigned*)wsv;
  u32* wsu = (u32*)((char*)wsv + 8192);
  u32* IN0u = wsu;
  u32* IN1u = wsu + 65536;
  u32* IN2u = wsu + 131072;
  u32* H2u  = wsu + 196608;
  u32* encbfu = wsu + ENC_OFF;
  u32* wqbfu  = wsu + WQ_OFF;

  const int w = blockIdx.x, tid = threadIdx.x;
  const int lane = tid & 63, r = tid >> 6;
  const int d = w & 1;                 // sync domain / batch half
  const int idx = w >> 1;              // 0..127 within domain
  const int jt = idx, bt = d;
  unsigned* barD = bar + d*1024;
  unsigned ep = 0;

  __shared__ __attribute__((aligned(16))) u32 SM[26752];
  u32*   stage = SM;
  float* scr   = (float*)(SM + 16384);
  u32*   xsu   = SM + 24576;
  float* sG4   = (float*)(SM + 25856);
  float* sc_c  = (float*)(SM + 26368);
  // attn aliases into stage region (disjoint phases):
  float* sBig   = (float*)SM;              // 4096 f
  float* sVec   = (float*)(SM + 4096);     // 512 f
  float* sSmall = (float*)(SM + 4608);     // 16 f

  // ---- prologue: weights -> registers (2 rows per wave) ----
  const int wrowA = ((r&3)<<9) + (jt<<2) + (r>>2);
  const int wrowB = wrowA + 2;
  float w0r[2][8][2], w1r[2][8][2], w2r[2][8][2], wx0[2][4];
  #pragma unroll
  for (int s=0;s<2;++s){
    const int wr = s ? wrowB : wrowA;
    #pragma unroll
    for (int i=0;i<8;++i){
      const int k = 2*(lane + (i<<6));
      if (k < 512){
        w0r[s][i][0] = Wih0[wr*592 + 80 + k];   w0r[s][i][1] = Wih0[wr*592 + 81 + k];
        w1r[s][i][0] = Wih1[(wr<<9) + k];       w1r[s][i][1] = Wih1[(wr<<9) + k + 1];
        w2r[s][i][0] = Wih2[(wr<<9) + k];       w2r[s][i][1] = Wih2[(wr<<9) + k + 1];
      } else {
        w0r[s][i][0] = Whh0[(wr<<9) + k - 512]; w0r[s][i][1] = Whh0[(wr<<9) + k - 511];
        w1r[s][i][0] = Whh1[(wr<<9) + k - 512]; w1r[s][i][1] = Whh1[(wr<<9) + k - 511];
        w2r[s][i][0] = Whh2[(wr<<9) + k - 512]; w2r[s][i][1] = Whh2[(wr<<9) + k - 511];
      }
    }
    #pragma unroll
    for (int m=0;m<4;++m)
      wx0[s][m] = (lane < 20) ? Wih0[wr*592 + (lane<<2) + m] : 0.f;
  }
  const float br0A=b0v[wrowA], br0B=b0v[wrowB];
  const float br1A=b1v[wrowA], br1B=b1v[wrowB];
  const float br2A=b2v[wrowA], br2B=b2v[wrowB];

  if (tid < 384) sc_c[tid] = 0.f;

  // ---- domain-local init: zero state (106496 u32/domain) ----
  for (int i = idx*NTHR + tid; i < 106496; i += 128*NTHR){
    u32* p;
    if (i < 98304){
      const int buf = i >> 15;
      const int r2  = i & 32767;
      const int par = r2 >> 14;
      const int r3  = r2 & 16383;
      const int b   = (d<<5) + (r3 >> 9);
      const int c   = r3 & 511;
      u32* base = (buf==0) ? IN0u : (buf==1) ? IN1u : IN2u;
      p = base + par*32768 + b*512 + c;
    } else {
      const int r3 = i - 98304;
      const int b  = (d<<5) + (r3 >> 8);
      p = H2u + b*256 + (r3 & 255);
    }
    st_sysu(p, 0u);
  }
  if (ebf){
    // enc bf16 (domain's 32 batches)
    for (int i = idx*NTHR + tid; i < 4194304; i += 128*NTHR){
      const int gi = (d<<22) + i;
      st_sysu(encbfu + gi, cvtpk(enc[2*(size_t)gi], enc[2*(size_t)gi+1]));
    }
    // per-domain Wq bf16 copy
    u32* wqd = wqbfu + d*131072;
    for (int i = idx*NTHR + tid; i < 131072; i += 128*NTHR){
      const int k = i >> 8, ee = (i & 255) << 1;
      st_sysu(wqd + i, cvtpk(Wq[(k<<9) + ee], Wq[(k<<9) + ee + 1]));
    }
  }
  gsync(barD, idx, ep);

  for (int t=0; t<255; ++t){
    const int p = t & 1, np = p ^ 1;
    u32* IN0p = IN0u + p*32768;  u32* IN0n = IN0u + np*32768;
    u32* IN1p = IN1u + p*32768;  u32* IN1n = IN1u + np*32768;
    u32* IN2p = IN2u + p*32768;  u32* IN2n = IN2u + np*32768;

    lstm_layer<true >(jt,bt,tid, w0r, wx0, br0A, br0B, IN0p, sc_c,
                      IN0n+256, 512, IN1p, 512, stage,scr,xsu,sG4, tgt, t);
    gsync(barD,idx,ep);
    lstm_layer<false>(jt,bt,tid, w1r, wx0, br1A, br1B, IN1p, sc_c+128,
                      IN1n+256, 512, IN2p, 512, stage,scr,xsu,sG4, tgt, t);
    gsync(barD,idx,ep);
    lstm_layer<false>(jt,bt,tid, w2r, wx0, br2A, br2B, IN2p, sc_c+256,
                      IN2n+256, 512, H2u, 256, stage,scr,xsu,sG4, tgt, t);
    gsync(barD,idx,ep);

    // ---- attnA': all 128 WGs. (b_loc = idx&31, sq = idx>>5).
    //      q computed redundantly (4x) then 128-row online softmax. ----
    {
      const int b_loc = idx & 31, sq = idx >> 5;
      const int b = (d<<5) + b_loc;
      const int len = lens[b];
      // h2 -> sVec (fp32)
      if (tid < 256){
        const u32 u = aldu(H2u + b*256 + tid);
        sVec[2*tid]   = bflo(u);
        sVec[2*tid+1] = bfhi(u);
      }
      __syncthreads();
      // q[e=tid] = sum_k h2[k] * Wq[k][e]
      float qa = 0.f;
      if (ebf){
        const u32* wqb = wqbfu + d*131072 + (tid>>1);
        const u32 sel = tid & 1;
        #pragma unroll 4
        for (int k=0;k<512;++k){
          const u32 u = wqb[k<<8];                   // normal cached (L2-hot)
          qa = fmaf(sVec[k], sel ? bfhi(u) : bflo(u), qa);
        }
      } else {
        const float* wqp = Wq + tid;
        #pragma unroll 4
        for (int k=0;k<512;++k) qa = fmaf(sVec[k], wqp[(size_t)k<<9], qa);
      }
      __syncthreads();                               // h2 reads done
      sVec[tid] = qa;                                // sVec now holds q
      __syncthreads();

      const int wv = tid >> 6;
      const float4 qA = *(const float4*)(sVec + (lane<<3));
      const float4 qB = *(const float4*)(sVec + (lane<<3) + 4);
      float mr = -3.0e38f, lr = 0.f;
      float c0=0,c1=0,c2=0,c3=0,c4=0,c5=0,c6=0,c7=0;
      const float scale = 0.04419417382415922f;      // 1/sqrt(512)
      if (ebf){
        const u32* ebase = encbfu + (((size_t)b)<<17) + (lane<<2);
        #pragma unroll 1
        for (int rr=0; rr<16; ++rr){
          const int srow = (sq<<7) + (wv<<4) + rr;   // wave-uniform
          if (srow >= len) break;                    // rows monotonic
          const uint4 eu = *(const uint4*)(ebase + ((size_t)srow<<8));
          const float e0=bflo(eu.x), e1=bfhi(eu.x), e2=bflo(eu.y), e3=bfhi(eu.y);
          const float e4=bflo(eu.z), e5=bfhi(eu.z), e6=bflo(eu.w), e7=bfhi(eu.w);
          float d0 = qA.x*e0, d1 = qA.y*e1, d2 = qA.z*e2, d3 = qA.w*e3;
          d0 = fmaf(qB.x, e4, d0); d1 = fmaf(qB.y, e5, d1);
          d2 = fmaf(qB.z, e6, d2); d3 = fmaf(qB.w, e7, d3);
          float dd = wred_sum((d0+d1)+(d2+d3));
          const float sc = dd*scale;
          const float mn = fmaxf(mr, sc);
          const float sf = __expf(mr - mn);
          const float pe = __expf(sc - mn);
          lr = fmaf(lr, sf, pe);
          c0 = fmaf(c0, sf, pe*e0); c1 = fmaf(c1, sf, pe*e1);
          c2 = fmaf(c2, sf, pe*e2); c3 = fmaf(c3, sf, pe*e3);
          c4 = fmaf(c4, sf, pe*e4); c5 = fmaf(c5, sf, pe*e5);
          c6 = fmaf(c6, sf, pe*e6); c7 = fmaf(c7, sf, pe*e7);
          mr = mn;
        }
      } else {
        #pragma unroll 1
        for (int rr=0; rr<16; ++rr){
          const int srow = (sq<<7) + (wv<<4) + rr;
          if (srow >= len) break;
          const float* ep2 = enc + (((size_t)(b<<9)+srow)<<9) + (lane<<3);
          const float4 e0v = *(const float4*)(ep2);
          const float4 e1v = *(const float4*)(ep2+4);
          float d0 = qA.x*e0v.x, d1 = qA.y*e0v.y, d2 = qA.z*e0v.z, d3 = qA.w*e0v.w;
          d0 = fmaf(qB.x, e1v.x, d0); d1 = fmaf(qB.y, e1v.y, d1);
          d2 = fmaf(qB.z, e1v.z, d2); d3 = fmaf(qB.w, e1v.w, d3);
          float dd = wred_sum((d0+d1)+(d2+d3));
          const float sc = dd*scale;
          const float mn = fmaxf(mr, sc);
          const float sf = __expf(mr - mn);
          const float pe = __expf(sc - mn);
          lr = fmaf(lr, sf, pe);
          c0 = fmaf(c0, sf, pe*e0v.x); c1 = fmaf(c1, sf, pe*e0v.y);
          c2 = fmaf(c2, sf, pe*e0v.z); c3 = fmaf(c3, sf, pe*e0v.w);
          c4 = fmaf(c4, sf, pe*e1v.x); c5 = fmaf(c5, sf, pe*e1v.y);
          c6 = fmaf(c6, sf, pe*e1v.z); c7 = fmaf(c7, sf, pe*e1v.w);
          mr = mn;
        }
      }
      if (lane==0){ sSmall[wv] = mr; sSmall[8+wv] = lr; }
      {
        float4 v0 = {c0,c1,c2,c3}, v1 = {c4,c5,c6,c7};
        *(float4*)(sBig + (wv<<9) + (lane<<3))     = v0;
        *(float4*)(sBig + (wv<<9) + (lane<<3) + 4) = v1;
      }
      __syncthreads();
      float M = sSmall[0];
      #pragma unroll
      for (int i=1;i<8;++i) M = fmaxf(M, sSmall[i]);
      float L = 0.f, acc = 0.f;
      #pragma unroll
      for (int i=0;i<8;++i){
        const float A = __expf(sSmall[i]-M);
        L   = fmaf(A, sSmall[8+i], L);
        acc = fmaf(A, sBig[(i<<9)+tid], acc);
      }
      // partial ctx (unnormalized) + (M,L) to fp32 state via bit-exact u32
      float* PC = (float*)(wsu + 212992);            // [4][64][512] f
      st_sysu((u32*)&PC[(((sq<<6)+b)<<9)+tid], __float_as_uint(acc));
      if (tid==0){
        float* MSS = PC + 131072;                    // after PC region
        st_sysu((u32*)&MSS[(((sq<<6)+b)<<1)],   __float_as_uint(M));
        st_sysu((u32*)&MSS[(((sq<<6)+b)<<1)+1], __float_as_uint(L));
      }
    }
    gsync(barD,idx,ep);

    // ---- attnB: combine + FC + out (32 WGs/domain: idx<32) ----
    if (idx < 32){
      const int b = (d<<5) + idx;
      float* PC  = (float*)(wsu + 212992);
      float* MSS = PC + 131072;
      const float m0 = __uint_as_float(aldu((u32*)&MSS[(b)<<1]));
      const float S0 = __uint_as_float(aldu((u32*)&MSS[((b)<<1)+1]));
      const float m1 = __uint_as_float(aldu((u32*)&MSS[(64+b)<<1]));
      const float S1 = __uint_as_float(aldu((u32*)&MSS[((64+b)<<1)+1]));
      const float m2 = __uint_as_float(aldu((u32*)&MSS[(128+b)<<1]));
      const float S2 = __uint_as_float(aldu((u32*)&MSS[((128+b)<<1)+1]));
      const float m3 = __uint_as_float(aldu((u32*)&MSS[(192+b)<<1]));
      const float S3 = __uint_as_float(aldu((u32*)&MSS[((192+b)<<1)+1]));
      const float M  = fmaxf(fmaxf(m0,m1), fmaxf(m2,m3));
      const float a0=__expf(m0-M), a1=__expf(m1-M), a2=__expf(m2-M), a3=__expf(m3-M);
      const float inv = 1.f/(a0*S0 + a1*S1 + a2*S2 + a3*S3);
      const float c =
        (a0*__uint_as_float(aldu((u32*)&PC[(b<<9)+tid]))
       + a1*__uint_as_float(aldu((u32*)&PC[((64+b)<<9)+tid]))
       + a2*__uint_as_float(aldu((u32*)&PC[((128+b)<<9)+tid]))
       + a3*__uint_as_float(aldu((u32*)&PC[((192+b)<<9)+tid]))) * inv;
      const float cpr = __shfl(c, tid^1, 64);
      if (!(tid&1)) st_sysu(IN0n + b*512 + (tid>>1), cvtpk(c, cpr));
      sVec[tid] = c;
      __syncthreads();
      if (tid < 80){
        float acc2 = 0.f;
        #pragma unroll 4
        for (int e2=0;e2<512;++e2) acc2 = fmaf(sVec[e2], Wfc[e2*80+tid], acc2);
        out[((size_t)b*255 + t)*80 + tid] = acc2 + bfc[tid];
      }
    }
    gsync(barD,idx,ep);
  }
}

extern "C" void kernel_launch(void* const* d_in, const int* in_sizes, int n_in,
                              void* d_out, int out_size, void* d_ws, size_t ws_size,
                              hipStream_t stream) {
  const float* tgt  = (const float*)d_in[0];
  const float* enc  = (const float*)d_in[1];
  const int*   lens = (const int*)  d_in[2];
  const float* Wih0 = (const float*)d_in[3];
  const float* Whh0 = (const float*)d_in[4];
  const float* b0   = (const float*)d_in[5];
  const float* Wih1 = (const float*)d_in[6];
  const float* Whh1 = (const float*)d_in[7];
  const float* b1   = (const float*)d_in[8];
  const float* Wih2 = (const float*)d_in[9];
  const float* Whh2 = (const float*)d_in[10];
  const float* b2   = (const float*)d_in[11];
  const float* Wq   = (const float*)d_in[12];
  const float* Wfc  = (const float*)d_in[13];
  const float* bfc  = (const float*)d_in[14];

  const size_t need = 8192ull + ((size_t)WQ_OFF + 2ull*(size_t)WQ_CNT)*4ull;
  const int ebf = (ws_size >= need) ? 1 : 0;

  hipMemsetAsync(d_ws, 0, 8192, stream);   // barrier flags (2 domains)
  sd_kernel<<<NBLK, NTHR, 0, stream>>>(tgt, enc, lens,
                                       Wih0, Whh0, b0,
                                       Wih1, Whh1, b1,
                                       Wih2, Whh2, b2,
                                       Wq, Wfc, bfc,
                                       (float*)d_out, d_ws, ebf);
}